// Round 4
// baseline (131.618 us; speedup 1.0000x reference)
//
#include <hip/hip_runtime.h>
#include <stdint.h>

#define NFEAT  128
#define NREL   3

typedef short short8 __attribute__((ext_vector_type(8)));
typedef float f32x4  __attribute__((ext_vector_type(4)));

// ---------- helpers ----------
__device__ __forceinline__ uint32_t f2bf(float x) {
    uint32_t u = __builtin_bit_cast(uint32_t, x);
    uint32_t r = (u + 0x7FFFu + ((u >> 16) & 1u)) >> 16;  // RNE
    return r & 0xFFFFu;
}
__device__ __forceinline__ float bf2f(uint32_t b) {
    uint32_t u = b << 16;
    return __builtin_bit_cast(float, u);
}

// ---------- K_prep: W[r][k][o] fp32 -> Wt[r][o][k] bf16 (coalesced writes)
//            + block 0 zeroes bincnt ----------
__global__ __launch_bounds__(256) void k_prep_w(
    const float* __restrict__ W, uint16_t* __restrict__ Wt, int* __restrict__ bincnt)
{
    const int tid = blockIdx.x * 256 + threadIdx.x;
    if (blockIdx.x == 0) bincnt[threadIdx.x] = 0;
    if (tid >= NREL * NFEAT * 16) return;
    const int k8 = tid & 15;           // 8-wide chunk along k
    const int o  = (tid >> 4) & 127;
    const int r  = tid >> 11;
    const float* Wr = W + (size_t)r * NFEAT * NFEAT;
    uint32_t pk[4];
    #pragma unroll
    for (int q = 0; q < 4; q++) {
        float lo = Wr[(size_t)(k8 * 8 + q * 2)     * NFEAT + o];
        float hi = Wr[(size_t)(k8 * 8 + q * 2 + 1) * NFEAT + o];
        pk[q] = f2bf(lo) | (f2bf(hi) << 16);
    }
    uint4 v = make_uint4(pk[0], pk[1], pk[2], pk[3]);
    *reinterpret_cast<uint4*>(&Wt[(size_t)r * NFEAT * NFEAT + (size_t)o * NFEAT + k8 * 8]) = v;
}

// ---------- K1: grouped GEMM (blocks < GB) + bin histogram (blocks >= GB) ----
// GEMM: BM=64, full N=128, K=128. B-fragments read directly from global Wt
// (L2-hot, shared by all blocks). LDS only holds the swizzled A tile (16 KB).
__global__ __launch_bounds__(256) void k_gemm_hist(
    const float* __restrict__ feat, const uint16_t* __restrict__ Wt,
    uint16_t* __restrict__ hr, int N,
    const int* __restrict__ dst, int* __restrict__ bincnt, int E, int GB)
{
    __shared__ uint16_t ldsA[64 * 128];    // 16 KB, [row][k] swizzled
    __shared__ int h[256];

    const int t = threadIdx.x;

    if (blockIdx.x >= GB) {
        // ---------------- histogram part ----------------
        h[t] = 0;
        __syncthreads();
        int e = (blockIdx.x - GB) * 2048 + t;
        #pragma unroll
        for (int j = 0; j < 8; j++, e += 256)
            if (e < E) atomicAdd(&h[dst[e] >> 8], 1);
        __syncthreads();
        if (h[t]) atomicAdd(&bincnt[t], h[t]);
        return;
    }

    // ---------------- GEMM part ----------------
    const int lane = t & 63;
    const int w    = t >> 6;
    const int n0   = blockIdx.x * 64;

    // stage A (fp32 -> bf16, swizzled)
    {
        const int kq = t & 15;
        const int rq = t >> 4;
        #pragma unroll
        for (int rr = 0; rr < 4; rr++) {
            const int row = rr * 16 + rq;
            const int n = n0 + row;
            uint4 pk = make_uint4(0, 0, 0, 0);
            if (n < N) {
                const float4* p = reinterpret_cast<const float4*>(&feat[(size_t)n * NFEAT + kq * 8]);
                float4 v0 = p[0], v1 = p[1];
                pk.x = f2bf(v0.x) | (f2bf(v0.y) << 16);
                pk.y = f2bf(v0.z) | (f2bf(v0.w) << 16);
                pk.z = f2bf(v1.x) | (f2bf(v1.y) << 16);
                pk.w = f2bf(v1.z) | (f2bf(v1.w) << 16);
            }
            uint32_t byte = (uint32_t)(row * 256 + kq * 16) ^ ((uint32_t)(row & 7) << 4);
            *reinterpret_cast<uint4*>(reinterpret_cast<char*>(ldsA) + byte) = pk;
        }
    }
    __syncthreads();

    const int rowf = lane & 15;
    const int kb   = lane >> 4;

    // A fragments once (row fixed across relations)
    short8 a[4];
    {
        const int row = w * 16 + rowf;
        #pragma unroll
        for (int ks = 0; ks < 4; ks++) {
            uint32_t byte = (uint32_t)(row * 256 + ks * 64 + kb * 16) ^ ((uint32_t)(row & 7) << 4);
            a[ks] = *reinterpret_cast<const short8*>(reinterpret_cast<char*>(ldsA) + byte);
        }
    }

    for (int r = 0; r < NREL; r++) {
        const uint16_t* Wr = Wt + (size_t)r * NFEAT * NFEAT;
        f32x4 acc[8];
        #pragma unroll
        for (int cf = 0; cf < 8; cf++) acc[cf] = (f32x4){0.f, 0.f, 0.f, 0.f};

        #pragma unroll
        for (int cf = 0; cf < 8; cf++) {
            const int col = cf * 16 + rowf;
            #pragma unroll
            for (int ks = 0; ks < 4; ks++) {
                short8 b = *reinterpret_cast<const short8*>(
                    &Wr[(size_t)col * NFEAT + ks * 32 + kb * 8]);
                acc[cf] = __builtin_amdgcn_mfma_f32_16x16x32_bf16(a[ks], b, acc[cf], 0, 0, 0);
            }
        }

        // D layout: col = lane&15 (rowf), row = kb*4 + j
        #pragma unroll
        for (int cf = 0; cf < 8; cf++) {
            #pragma unroll
            for (int j = 0; j < 4; j++) {
                const int n = n0 + w * 16 + kb * 4 + j;
                if (n < N)
                    hr[((size_t)r * N + n) * NFEAT + cf * 16 + rowf] = (uint16_t)f2bf(acc[cf][j]);
            }
        }
    }
}

// ---------- K3: single-block scan of bin counts ----------
__global__ __launch_bounds__(256) void k_binscan(
    const int* __restrict__ bincnt, int* __restrict__ binoff,
    int* __restrict__ bincursor, int* __restrict__ offsets,
    int N, int E, int nbins)
{
    __shared__ int sm[256];
    const int t = threadIdx.x;
    int v = (t < nbins) ? bincnt[t] : 0;
    sm[t] = v;
    __syncthreads();
    for (int s = 1; s < 256; s <<= 1) {
        int a = (t >= s) ? sm[t - s] : 0;
        __syncthreads();
        sm[t] += a;
        __syncthreads();
    }
    int excl = sm[t] - v;
    if (t < nbins) { binoff[t] = excl; bincursor[t] = excl; }
    if (t == 0) { binoff[nbins] = E; offsets[N] = E; }
}

// ---------- K4: bin-grouped fill of packed records ----------
// record: (src | rel<<16 | dstlocal<<18, norm)
__global__ __launch_bounds__(256) void k_binfill(
    const int* __restrict__ dst, const int* __restrict__ src,
    const int* __restrict__ rel, const float* __restrict__ norm,
    int* __restrict__ bincursor, uint2* __restrict__ binbuf, int E)
{
    __shared__ int hist[256];
    __shared__ int base[256];
    __shared__ int rank[256];
    const int t = threadIdx.x;
    const int e0 = blockIdx.x * 2048;

    hist[t] = 0;
    __syncthreads();

    int myBin[8], myDl[8];
    #pragma unroll
    for (int j = 0; j < 8; j++) {
        int e = e0 + t + j * 256;
        int b = -1, dl = 0;
        if (e < E) {
            int d = dst[e];
            b = d >> 8;
            dl = d & 255;
            atomicAdd(&hist[b], 1);
        }
        myBin[j] = b;
        myDl[j] = dl;
    }
    __syncthreads();

    int h = hist[t];
    if (h > 0) base[t] = atomicAdd(&bincursor[t], h);
    rank[t] = 0;
    __syncthreads();

    #pragma unroll
    for (int j = 0; j < 8; j++) {
        int e = e0 + t + j * 256;
        if (myBin[j] >= 0) {
            int p = base[myBin[j]] + atomicAdd(&rank[myBin[j]], 1);
            uint32_t px = (uint32_t)src[e] | ((uint32_t)rel[e] << 16) | ((uint32_t)myDl[j] << 18);
            binbuf[p] = make_uint2(px, __builtin_bit_cast(uint32_t, norm[e]));
        }
    }
}

// ---------- K5: per-bin dst-sort -> CSR offsets + sorted meta ----------
__global__ __launch_bounds__(256) void k_binsort(
    const uint2* __restrict__ binbuf, const int* __restrict__ binoff,
    uint2* __restrict__ meta, int* __restrict__ offsets, int N)
{
    __shared__ int sm[256];
    __shared__ int cur[256];
    const int b = blockIdx.x;
    const int t = threadIdx.x;
    const int base = binoff[b];
    const int cnt  = binoff[b + 1] - base;

    sm[t] = 0;
    __syncthreads();
    for (int i = t; i < cnt; i += 256) {
        uint2 r = binbuf[base + i];
        atomicAdd(&sm[(r.x >> 18) & 255], 1);
    }
    __syncthreads();
    int v = sm[t];
    __syncthreads();
    sm[t] = v;
    __syncthreads();
    for (int s = 1; s < 256; s <<= 1) {
        int a = (t >= s) ? sm[t - s] : 0;
        __syncthreads();
        sm[t] += a;
        __syncthreads();
    }
    int excl = sm[t] - v;
    int n = b * 256 + t;
    if (n < N) offsets[n] = base + excl;
    cur[t] = excl;
    __syncthreads();

    for (int i = t; i < cnt; i += 256) {
        uint2 r = binbuf[base + i];
        int dl = (r.x >> 18) & 255;
        int p = atomicAdd(&cur[dl], 1);
        meta[base + p] = make_uint2(r.x & 0x3FFFFu, r.y);
    }
}

// ---------- K6: pull aggregation + ReLU (8 gathers in flight) ----------
__global__ __launch_bounds__(256) void k_aggregate(
    const uint16_t* __restrict__ hr, const int* __restrict__ offsets,
    const uint2* __restrict__ meta, float* __restrict__ out, int N)
{
    const int wid  = threadIdx.x >> 6;
    const int lane = threadIdx.x & 63;
    const int n = blockIdx.x * 4 + wid;
    if (n >= N) return;

    const int start = offsets[n];
    const int end   = offsets[n + 1];
    const int c = lane * 2;

    float a0 = 0.f, a1 = 0.f, b0 = 0.f, b1 = 0.f;
    int idx = start;

    for (; idx + 7 < end; idx += 8) {
        uint2 m[8];
        #pragma unroll
        for (int j = 0; j < 8; j++) m[j] = meta[idx + j];
        uint32_t v[8];
        #pragma unroll
        for (int j = 0; j < 8; j++)
            v[j] = *reinterpret_cast<const uint32_t*>(
                &hr[((size_t)(m[j].x >> 16) * N + (m[j].x & 0xFFFFu)) * NFEAT + c]);
        #pragma unroll
        for (int j = 0; j < 8; j += 2) {
            float w0 = __builtin_bit_cast(float, m[j].y);
            float w1 = __builtin_bit_cast(float, m[j + 1].y);
            a0 += w0 * bf2f(v[j] & 0xFFFFu);     a1 += w0 * bf2f(v[j] >> 16);
            b0 += w1 * bf2f(v[j + 1] & 0xFFFFu); b1 += w1 * bf2f(v[j + 1] >> 16);
        }
    }
    for (; idx + 3 < end; idx += 4) {
        uint2 m[4];
        #pragma unroll
        for (int j = 0; j < 4; j++) m[j] = meta[idx + j];
        uint32_t v[4];
        #pragma unroll
        for (int j = 0; j < 4; j++)
            v[j] = *reinterpret_cast<const uint32_t*>(
                &hr[((size_t)(m[j].x >> 16) * N + (m[j].x & 0xFFFFu)) * NFEAT + c]);
        #pragma unroll
        for (int j = 0; j < 4; j += 2) {
            float w0 = __builtin_bit_cast(float, m[j].y);
            float w1 = __builtin_bit_cast(float, m[j + 1].y);
            a0 += w0 * bf2f(v[j] & 0xFFFFu);     a1 += w0 * bf2f(v[j] >> 16);
            b0 += w1 * bf2f(v[j + 1] & 0xFFFFu); b1 += w1 * bf2f(v[j + 1] >> 16);
        }
    }
    for (; idx < end; idx++) {
        uint2 m = meta[idx];
        uint32_t v = *reinterpret_cast<const uint32_t*>(
            &hr[((size_t)(m.x >> 16) * N + (m.x & 0xFFFFu)) * NFEAT + c]);
        float wgt = __builtin_bit_cast(float, m.y);
        a0 += wgt * bf2f(v & 0xFFFFu);
        a1 += wgt * bf2f(v >> 16);
    }

    float2 o;
    o.x = fmaxf(a0 + b0, 0.f);
    o.y = fmaxf(a1 + b1, 0.f);
    *reinterpret_cast<float2*>(&out[(size_t)n * NFEAT + c]) = o;
}

// ---------- launch ----------
extern "C" void kernel_launch(void* const* d_in, const int* in_sizes, int n_in,
                              void* d_out, int out_size, void* d_ws, size_t ws_size,
                              hipStream_t stream)
{
    const float* feat = (const float*)d_in[0];
    const float* W    = (const float*)d_in[1];
    const float* norm = (const float*)d_in[2];
    const int*   src  = (const int*)d_in[3];
    const int*   dst  = (const int*)d_in[4];
    const int*   rel  = (const int*)d_in[5];
    float* out = (float*)d_out;

    const int N = in_sizes[0] / NFEAT;      // 50000
    const int E = in_sizes[2];              // 800000
    const int NBINS = (N + 255) / 256;      // 196
    const int GB = (N + 63) / 64;           // gemm blocks
    const int HB = (E + 2047) / 2048;       // hist blocks

    char* ws = (char*)d_ws;
    size_t off = 0;
    auto alloc = [&](size_t bytes) -> char* {
        char* p = ws + off;
        off += (bytes + 63) & ~(size_t)63;
        return p;
    };
    uint16_t* hr    = (uint16_t*)alloc((size_t)NREL * N * NFEAT * 2);  // 38.4 MB
    uint16_t* Wt    = (uint16_t*)alloc((size_t)NREL * NFEAT * NFEAT * 2);
    int* bincnt     = (int*)alloc(256 * 4);
    int* binoff     = (int*)alloc(257 * 4);
    int* bincursor  = (int*)alloc(256 * 4);
    int* offsets    = (int*)alloc((size_t)(N + 1) * 4);
    uint2* meta     = (uint2*)alloc((size_t)E * 8);                    // 6.4 MB
    (void)ws_size;

    // binbuf (6.4 MB) aliases d_out (25.6 MB): fully written by k_binfill before
    // k_binsort reads it; k_aggregate fully overwrites out afterwards.
    uint2* binbuf = (uint2*)d_out;

    k_prep_w<<<(NREL * NFEAT * 16 + 255) / 256, 256, 0, stream>>>(W, Wt, bincnt);
    k_gemm_hist<<<GB + HB, 256, 0, stream>>>(feat, Wt, hr, N, dst, bincnt, E, GB);
    k_binscan<<<1, 256, 0, stream>>>(bincnt, binoff, bincursor, offsets, N, E, NBINS);
    k_binfill<<<HB, 256, 0, stream>>>(dst, src, rel, norm, bincursor, binbuf, E);
    k_binsort<<<NBINS, 256, 0, stream>>>(binbuf, binoff, meta, offsets, N);
    k_aggregate<<<(N + 3) / 4, 256, 0, stream>>>(hr, offsets, meta, out, N);
}

// Round 5
// 107.408 us; speedup vs baseline: 1.2254x; 1.2254x over previous
//
#include <hip/hip_runtime.h>
#include <stdint.h>

#define NFEAT  128
#define NREL   3

typedef short short8 __attribute__((ext_vector_type(8)));
typedef float f32x4  __attribute__((ext_vector_type(4)));

// ---------- helpers ----------
__device__ __forceinline__ uint32_t f2bf(float x) {
    uint32_t u = __builtin_bit_cast(uint32_t, x);
    uint32_t r = (u + 0x7FFFu + ((u >> 16) & 1u)) >> 16;  // RNE
    return r & 0xFFFFu;
}
__device__ __forceinline__ float bf2f(uint32_t b) {
    uint32_t u = b << 16;
    return __builtin_bit_cast(float, u);
}

// ---------- K_prep: W[r][k][o] fp32 -> Wt[r][o][k] bf16 (coalesced writes)
//            + block 0 zeroes bincnt ----------
__global__ __launch_bounds__(256) void k_prep_w(
    const float* __restrict__ W, uint16_t* __restrict__ Wt, int* __restrict__ bincnt)
{
    const int tid = blockIdx.x * 256 + threadIdx.x;
    if (blockIdx.x == 0) bincnt[threadIdx.x] = 0;
    if (tid >= NREL * NFEAT * 16) return;
    const int k8 = tid & 15;           // 8-wide chunk along k
    const int o  = (tid >> 4) & 127;
    const int r  = tid >> 11;
    const float* Wr = W + (size_t)r * NFEAT * NFEAT;
    uint32_t pk[4];
    #pragma unroll
    for (int q = 0; q < 4; q++) {
        float lo = Wr[(size_t)(k8 * 8 + q * 2)     * NFEAT + o];
        float hi = Wr[(size_t)(k8 * 8 + q * 2 + 1) * NFEAT + o];
        pk[q] = f2bf(lo) | (f2bf(hi) << 16);
    }
    uint4 v = make_uint4(pk[0], pk[1], pk[2], pk[3]);
    *reinterpret_cast<uint4*>(&Wt[(size_t)r * NFEAT * NFEAT + (size_t)o * NFEAT + k8 * 8]) = v;
}

// ---------- K1: grouped GEMM hr[r] = feat @ W[r] via bf16 MFMA ----------
// r3-proven structure: A and B both staged in swizzled LDS. BM=64, BN=128, K=128.
__global__ __launch_bounds__(256) void k_gemm_mfma(
    const float* __restrict__ feat, const uint16_t* __restrict__ Wt,
    uint16_t* __restrict__ hr, int N)
{
    __shared__ uint16_t ldsA[64 * 128];    // 16 KB, [row][k] swizzled
    __shared__ uint16_t ldsB[128 * 128];   // 32 KB, [ocol][k] swizzled

    const int t    = threadIdx.x;
    const int lane = t & 63;
    const int w    = t >> 6;
    const int n0   = blockIdx.x * 64;

    // stage A (fp32 -> bf16, swizzled)
    {
        const int kq = t & 15;
        const int rq = t >> 4;
        #pragma unroll
        for (int rr = 0; rr < 4; rr++) {
            const int row = rr * 16 + rq;
            const int n = n0 + row;
            uint4 pk = make_uint4(0, 0, 0, 0);
            if (n < N) {
                const float4* p = reinterpret_cast<const float4*>(&feat[(size_t)n * NFEAT + kq * 8]);
                float4 v0 = p[0], v1 = p[1];
                pk.x = f2bf(v0.x) | (f2bf(v0.y) << 16);
                pk.y = f2bf(v0.z) | (f2bf(v0.w) << 16);
                pk.z = f2bf(v1.x) | (f2bf(v1.y) << 16);
                pk.w = f2bf(v1.z) | (f2bf(v1.w) << 16);
            }
            uint32_t byte = (uint32_t)(row * 256 + kq * 16) ^ ((uint32_t)(row & 7) << 4);
            *reinterpret_cast<uint4*>(reinterpret_cast<char*>(ldsA) + byte) = pk;
        }
    }

    const int rowf = lane & 15;
    const int kb   = lane >> 4;

    for (int r = 0; r < NREL; r++) {
        // stage B = Wt[r] (bf16, swizzled)
        {
            const int kq = t & 15;
            const int rq = t >> 4;
            const uint16_t* Wr = Wt + (size_t)r * NFEAT * NFEAT;
            #pragma unroll
            for (int rr = 0; rr < 8; rr++) {
                const int row = rr * 16 + rq;
                uint4 v = *reinterpret_cast<const uint4*>(&Wr[(size_t)row * NFEAT + kq * 8]);
                uint32_t byte = (uint32_t)(row * 256 + kq * 16) ^ ((uint32_t)(row & 7) << 4);
                *reinterpret_cast<uint4*>(reinterpret_cast<char*>(ldsB) + byte) = v;
            }
        }
        __syncthreads();

        short8 a[4];
        {
            const int row = w * 16 + rowf;
            #pragma unroll
            for (int ks = 0; ks < 4; ks++) {
                uint32_t byte = (uint32_t)(row * 256 + ks * 64 + kb * 16) ^ ((uint32_t)(row & 7) << 4);
                a[ks] = *reinterpret_cast<const short8*>(reinterpret_cast<char*>(ldsA) + byte);
            }
        }

        f32x4 acc[8];
        #pragma unroll
        for (int cf = 0; cf < 8; cf++) acc[cf] = (f32x4){0.f, 0.f, 0.f, 0.f};

        #pragma unroll
        for (int cf = 0; cf < 8; cf++) {
            const int col = cf * 16 + rowf;
            #pragma unroll
            for (int ks = 0; ks < 4; ks++) {
                uint32_t byte = (uint32_t)(col * 256 + ks * 64 + kb * 16) ^ ((uint32_t)(col & 7) << 4);
                short8 b = *reinterpret_cast<const short8*>(reinterpret_cast<char*>(ldsB) + byte);
                acc[cf] = __builtin_amdgcn_mfma_f32_16x16x32_bf16(a[ks], b, acc[cf], 0, 0, 0);
            }
        }

        #pragma unroll
        for (int cf = 0; cf < 8; cf++) {
            #pragma unroll
            for (int j = 0; j < 4; j++) {
                const int n = n0 + w * 16 + kb * 4 + j;
                if (n < N)
                    hr[((size_t)r * N + n) * NFEAT + cf * 16 + rowf] = (uint16_t)f2bf(acc[cf][j]);
            }
        }
        __syncthreads();
    }
}

// ---------- K2: per-bin histogram (bin = dst >> 8), LDS pre-aggregated ----------
__global__ __launch_bounds__(256) void k_binhist(
    const int* __restrict__ dst, int* __restrict__ bincnt, int E)
{
    __shared__ int h[256];
    const int t = threadIdx.x;
    h[t] = 0;
    __syncthreads();
    int e = blockIdx.x * 2048 + t;
    #pragma unroll
    for (int j = 0; j < 8; j++, e += 256)
        if (e < E) atomicAdd(&h[dst[e] >> 8], 1);
    __syncthreads();
    if (h[t]) atomicAdd(&bincnt[t], h[t]);
}

// ---------- K3: single-block scan of bin counts ----------
__global__ __launch_bounds__(256) void k_binscan(
    const int* __restrict__ bincnt, int* __restrict__ binoff,
    int* __restrict__ bincursor, int* __restrict__ offsets,
    int N, int E, int nbins)
{
    __shared__ int sm[256];
    const int t = threadIdx.x;
    int v = (t < nbins) ? bincnt[t] : 0;
    sm[t] = v;
    __syncthreads();
    for (int s = 1; s < 256; s <<= 1) {
        int a = (t >= s) ? sm[t - s] : 0;
        __syncthreads();
        sm[t] += a;
        __syncthreads();
    }
    int excl = sm[t] - v;
    if (t < nbins) { binoff[t] = excl; bincursor[t] = excl; }
    if (t == 0) { binoff[nbins] = E; offsets[N] = E; }
}

// ---------- K4: bin-grouped fill of packed records ----------
// record: (src | rel<<16 | dstlocal<<18, norm)
__global__ __launch_bounds__(256) void k_binfill(
    const int* __restrict__ dst, const int* __restrict__ src,
    const int* __restrict__ rel, const float* __restrict__ norm,
    int* __restrict__ bincursor, uint2* __restrict__ binbuf, int E)
{
    __shared__ int hist[256];
    __shared__ int base[256];
    __shared__ int rank[256];
    const int t = threadIdx.x;
    const int e0 = blockIdx.x * 2048;

    hist[t] = 0;
    __syncthreads();

    int myBin[8], myDl[8];
    #pragma unroll
    for (int j = 0; j < 8; j++) {
        int e = e0 + t + j * 256;
        int b = -1, dl = 0;
        if (e < E) {
            int d = dst[e];
            b = d >> 8;
            dl = d & 255;
            atomicAdd(&hist[b], 1);
        }
        myBin[j] = b;
        myDl[j] = dl;
    }
    __syncthreads();

    int h = hist[t];
    if (h > 0) base[t] = atomicAdd(&bincursor[t], h);
    rank[t] = 0;
    __syncthreads();

    #pragma unroll
    for (int j = 0; j < 8; j++) {
        int e = e0 + t + j * 256;
        if (myBin[j] >= 0) {
            int p = base[myBin[j]] + atomicAdd(&rank[myBin[j]], 1);
            uint32_t px = (uint32_t)src[e] | ((uint32_t)rel[e] << 16) | ((uint32_t)myDl[j] << 18);
            binbuf[p] = make_uint2(px, __builtin_bit_cast(uint32_t, norm[e]));
        }
    }
}

// ---------- K5: per-bin dst-sort -> CSR offsets + sorted meta ----------
__global__ __launch_bounds__(256) void k_binsort(
    const uint2* __restrict__ binbuf, const int* __restrict__ binoff,
    uint2* __restrict__ meta, int* __restrict__ offsets, int N)
{
    __shared__ int sm[256];
    __shared__ int cur[256];
    const int b = blockIdx.x;
    const int t = threadIdx.x;
    const int base = binoff[b];
    const int cnt  = binoff[b + 1] - base;

    sm[t] = 0;
    __syncthreads();
    for (int i = t; i < cnt; i += 256) {
        uint2 r = binbuf[base + i];
        atomicAdd(&sm[(r.x >> 18) & 255], 1);
    }
    __syncthreads();
    int v = sm[t];
    __syncthreads();
    sm[t] = v;
    __syncthreads();
    for (int s = 1; s < 256; s <<= 1) {
        int a = (t >= s) ? sm[t - s] : 0;
        __syncthreads();
        sm[t] += a;
        __syncthreads();
    }
    int excl = sm[t] - v;
    int n = b * 256 + t;
    if (n < N) offsets[n] = base + excl;
    cur[t] = excl;
    __syncthreads();

    for (int i = t; i < cnt; i += 256) {
        uint2 r = binbuf[base + i];
        int dl = (r.x >> 18) & 255;
        int p = atomicAdd(&cur[dl], 1);
        meta[base + p] = make_uint2(r.x & 0x3FFFFu, r.y);
    }
}

// ---------- K6: pull aggregation + ReLU (8 gathers in flight) ----------
__global__ __launch_bounds__(256) void k_aggregate(
    const uint16_t* __restrict__ hr, const int* __restrict__ offsets,
    const uint2* __restrict__ meta, float* __restrict__ out, int N)
{
    const int wid  = threadIdx.x >> 6;
    const int lane = threadIdx.x & 63;
    const int n = blockIdx.x * 4 + wid;
    if (n >= N) return;

    const int start = offsets[n];
    const int end   = offsets[n + 1];
    const int c = lane * 2;

    float a0 = 0.f, a1 = 0.f, b0 = 0.f, b1 = 0.f;
    int idx = start;

    for (; idx + 7 < end; idx += 8) {
        uint2 m[8];
        #pragma unroll
        for (int j = 0; j < 8; j++) m[j] = meta[idx + j];
        uint32_t v[8];
        #pragma unroll
        for (int j = 0; j < 8; j++)
            v[j] = *reinterpret_cast<const uint32_t*>(
                &hr[((size_t)(m[j].x >> 16) * N + (m[j].x & 0xFFFFu)) * NFEAT + c]);
        #pragma unroll
        for (int j = 0; j < 8; j += 2) {
            float w0 = __builtin_bit_cast(float, m[j].y);
            float w1 = __builtin_bit_cast(float, m[j + 1].y);
            a0 += w0 * bf2f(v[j] & 0xFFFFu);     a1 += w0 * bf2f(v[j] >> 16);
            b0 += w1 * bf2f(v[j + 1] & 0xFFFFu); b1 += w1 * bf2f(v[j + 1] >> 16);
        }
    }
    for (; idx + 3 < end; idx += 4) {
        uint2 m[4];
        #pragma unroll
        for (int j = 0; j < 4; j++) m[j] = meta[idx + j];
        uint32_t v[4];
        #pragma unroll
        for (int j = 0; j < 4; j++)
            v[j] = *reinterpret_cast<const uint32_t*>(
                &hr[((size_t)(m[j].x >> 16) * N + (m[j].x & 0xFFFFu)) * NFEAT + c]);
        #pragma unroll
        for (int j = 0; j < 4; j += 2) {
            float w0 = __builtin_bit_cast(float, m[j].y);
            float w1 = __builtin_bit_cast(float, m[j + 1].y);
            a0 += w0 * bf2f(v[j] & 0xFFFFu);     a1 += w0 * bf2f(v[j] >> 16);
            b0 += w1 * bf2f(v[j + 1] & 0xFFFFu); b1 += w1 * bf2f(v[j + 1] >> 16);
        }
    }
    for (; idx < end; idx++) {
        uint2 m = meta[idx];
        uint32_t v = *reinterpret_cast<const uint32_t*>(
            &hr[((size_t)(m.x >> 16) * N + (m.x & 0xFFFFu)) * NFEAT + c]);
        float wgt = __builtin_bit_cast(float, m.y);
        a0 += wgt * bf2f(v & 0xFFFFu);
        a1 += wgt * bf2f(v >> 16);
    }

    float2 o;
    o.x = fmaxf(a0 + b0, 0.f);
    o.y = fmaxf(a1 + b1, 0.f);
    *reinterpret_cast<float2*>(&out[(size_t)n * NFEAT + c]) = o;
}

// ---------- launch ----------
extern "C" void kernel_launch(void* const* d_in, const int* in_sizes, int n_in,
                              void* d_out, int out_size, void* d_ws, size_t ws_size,
                              hipStream_t stream)
{
    const float* feat = (const float*)d_in[0];
    const float* W    = (const float*)d_in[1];
    const float* norm = (const float*)d_in[2];
    const int*   src  = (const int*)d_in[3];
    const int*   dst  = (const int*)d_in[4];
    const int*   rel  = (const int*)d_in[5];
    float* out = (float*)d_out;

    const int N = in_sizes[0] / NFEAT;      // 50000
    const int E = in_sizes[2];              // 800000
    const int NBINS = (N + 255) / 256;      // 196
    const int HB = (E + 2047) / 2048;       // hist/fill blocks

    char* ws = (char*)d_ws;
    size_t off = 0;
    auto alloc = [&](size_t bytes) -> char* {
        char* p = ws + off;
        off += (bytes + 63) & ~(size_t)63;
        return p;
    };
    uint16_t* hr    = (uint16_t*)alloc((size_t)NREL * N * NFEAT * 2);  // 38.4 MB
    uint16_t* Wt    = (uint16_t*)alloc((size_t)NREL * NFEAT * NFEAT * 2);
    int* bincnt     = (int*)alloc(256 * 4);
    int* binoff     = (int*)alloc(257 * 4);
    int* bincursor  = (int*)alloc(256 * 4);
    int* offsets    = (int*)alloc((size_t)(N + 1) * 4);
    uint2* meta     = (uint2*)alloc((size_t)E * 8);                    // 6.4 MB
    (void)ws_size;

    // binbuf (6.4 MB) aliases d_out (25.6 MB): fully written by k_binfill before
    // k_binsort reads it; k_aggregate fully overwrites out afterwards.
    uint2* binbuf = (uint2*)d_out;

    k_prep_w<<<(NREL * NFEAT * 16 + 255) / 256, 256, 0, stream>>>(W, Wt, bincnt);
    k_gemm_mfma<<<(N + 63) / 64, 256, 0, stream>>>(feat, Wt, hr, N);
    k_binhist<<<HB, 256, 0, stream>>>(dst, bincnt, E);
    k_binscan<<<1, 256, 0, stream>>>(bincnt, binoff, bincursor, offsets, N, E, NBINS);
    k_binfill<<<HB, 256, 0, stream>>>(dst, src, rel, norm, bincursor, binbuf, E);
    k_binsort<<<NBINS, 256, 0, stream>>>(binbuf, binoff, meta, offsets, N);
    k_aggregate<<<(N + 3) / 4, 256, 0, stream>>>(hr, offsets, meta, out, N);
}